// Round 1
// 3759.217 us; speedup vs baseline: 1.0631x; 1.0631x over previous
//
#include <hip/hip_runtime.h>
#include <math.h>

#define Hh  8
#define Dd  512
#define SUB 256          // D/2
#define Nk  1024         // num_subkeys
#define TK  32           // top_k
#define Rr  8            // rows (b,c) per block
#define NT  256
#define W_ELEMS (65536 * 32)

// Phase-1 arithmetic: single accumulator per (row,key), strictly sequential
// FUSED-FMA chain over the contraction dim in natural order (d = 0..255).
// This is bit-identical to the previous kernel (and to BLAS-style per-element
// reduction); only the *loop structure* changed:
//   - 64 B of each key row consumed per step (4 back-to-back dwordx4 from one
//     64B-aligned line -> MSHR-merged, no L1-residency dependence)
//   - all 8 rows accumulated in one pass (key rows read ONCE, not twice)
// Tie-break everywhere: stable lowest-index (XLA TopK semantics).

__global__ __launch_bounds__(NT, 2)
void pk_kernel(const float* __restrict__ query,
               const float* __restrict__ keyl,
               const float* __restrict__ keyr,
               float* __restrict__ out)
{
    __shared__ float sc[Rr][Nk];          // 32 KB
    __shared__ float topv[2][Rr][TK];     // 2 KB
    __shared__ int   topi[2][Rr][TK];     // 2 KB

    const int bid  = blockIdx.x;
    const int h    = bid >> 10;           // h-major for L2 key locality
    const int tile = bid & 1023;
    const int bc0  = tile * Rr;
    const int t    = threadIdx.x;
    const int lane = t & 63;
    const int wave = t >> 6;

    for (int side = 0; side < 2; ++side) {
        const float* kbase = (side == 0 ? keyl : keyr) + (size_t)h * Nk * SUB;

        const float4* qrow[Rr];           // wave-uniform -> scalar loads
        #pragma unroll
        for (int r = 0; r < Rr; ++r)
            qrow[r] = (const float4*)(query +
                ((size_t)(bc0 + r) * Hh + h) * Dd + side * SUB);

        // ---- phase 1: sequential-FMA GEMV, full-line key reads ----
        for (int g = 0; g < 4; ++g) {
            const float4* krow = (const float4*)(kbase + (size_t)(g * 256 + t) * SUB);
            float acc[Rr] = {0.f, 0.f, 0.f, 0.f, 0.f, 0.f, 0.f, 0.f};

            #pragma unroll 2
            for (int js = 0; js < 16; ++js) {     // 16 steps x 16 floats
                // one full 64B line of this lane's key row, issued together
                float4 k0 = krow[4*js+0], k1 = krow[4*js+1],
                       k2 = krow[4*js+2], k3 = krow[4*js+3];
                #pragma unroll
                for (int r = 0; r < Rr; ++r) {
                    float4 q0 = qrow[r][4*js+0], q1 = qrow[r][4*js+1],
                           q2 = qrow[r][4*js+2], q3 = qrow[r][4*js+3];
                    float a = acc[r];
                    // strictly sequential fused chain, d ascending
                    a = fmaf(q0.x, k0.x, a); a = fmaf(q0.y, k0.y, a);
                    a = fmaf(q0.z, k0.z, a); a = fmaf(q0.w, k0.w, a);
                    a = fmaf(q1.x, k1.x, a); a = fmaf(q1.y, k1.y, a);
                    a = fmaf(q1.z, k1.z, a); a = fmaf(q1.w, k1.w, a);
                    a = fmaf(q2.x, k2.x, a); a = fmaf(q2.y, k2.y, a);
                    a = fmaf(q2.z, k2.z, a); a = fmaf(q2.w, k2.w, a);
                    a = fmaf(q3.x, k3.x, a); a = fmaf(q3.y, k3.y, a);
                    a = fmaf(q3.z, k3.z, a); a = fmaf(q3.w, k3.w, a);
                    acc[r] = a;
                }
            }
            #pragma unroll
            for (int r = 0; r < Rr; ++r)
                sc[r][g * 256 + t] = acc[r];
        }
        __syncthreads();

        // ---- phase 2: exact top-32 per row, two rows interleaved per wave ----
        {
            const int ra = wave, rb = wave + 4;
            float va[16], vb[16];
            #pragma unroll
            for (int i = 0; i < 16; ++i) {
                va[i] = sc[ra][lane + 64 * i];
                vb[i] = sc[rb][lane + 64 * i];
            }
            for (int it = 0; it < TK; ++it) {
                float av = va[0]; int ap = lane;
                float bv = vb[0]; int bp = lane;
                #pragma unroll
                for (int i = 1; i < 16; ++i) {
                    if (va[i] > av) { av = va[i]; ap = lane + 64 * i; }
                    if (vb[i] > bv) { bv = vb[i]; bp = lane + 64 * i; }
                }
                #pragma unroll
                for (int m = 1; m < 64; m <<= 1) {
                    float oav = __shfl_xor(av, m, 64); int oap = __shfl_xor(ap, m, 64);
                    float obv = __shfl_xor(bv, m, 64); int obp = __shfl_xor(bp, m, 64);
                    if (oav > av || (oav == av && oap < ap)) { av = oav; ap = oap; }
                    if (obv > bv || (obv == bv && obp < bp)) { bv = obv; bp = obp; }
                }
                if (lane == it) {
                    topv[side][ra][it] = av; topi[side][ra][it] = ap;
                    topv[side][rb][it] = bv; topi[side][rb][it] = bp;
                }
                if (lane == (ap & 63)) va[ap >> 6] = -INFINITY;
                if (lane == (bp & 63)) vb[bp >> 6] = -INFINITY;
            }
        }
        __syncthreads();
    }

    // ---- phase 3: 32x32 product sums, top-32, softmax; two rows interleaved ----
    {
        const int ra = wave, rb = wave + 4;
        float va[16], vb[16];
        #pragma unroll
        for (int i = 0; i < 16; ++i) {
            int pos = lane + 64 * i;                  // pos = a*32 + b
            va[i] = __fadd_rn(topv[0][ra][pos >> 5], topv[1][ra][pos & 31]);
            vb[i] = __fadd_rn(topv[0][rb][pos >> 5], topv[1][rb][pos & 31]);
        }
        float m0a = 0.0f, wva = 0.0f; int wpa = 0;
        float m0b = 0.0f, wvb = 0.0f; int wpb = 0;
        for (int it = 0; it < TK; ++it) {
            float av = va[0]; int ap = lane;
            float bv = vb[0]; int bp = lane;
            #pragma unroll
            for (int i = 1; i < 16; ++i) {
                if (va[i] > av) { av = va[i]; ap = lane + 64 * i; }
                if (vb[i] > bv) { bv = vb[i]; bp = lane + 64 * i; }
            }
            #pragma unroll
            for (int m = 1; m < 64; m <<= 1) {
                float oav = __shfl_xor(av, m, 64); int oap = __shfl_xor(ap, m, 64);
                float obv = __shfl_xor(bv, m, 64); int obp = __shfl_xor(bp, m, 64);
                if (oav > av || (oav == av && oap < ap)) { av = oav; ap = oap; }
                if (obv > bv || (obv == bv && obp < bp)) { bv = obv; bp = obp; }
            }
            if (it == 0) { m0a = av; m0b = bv; }      // rank 0 = max
            if (lane == it) { wva = av; wpa = ap; wvb = bv; wpb = bp; }
            if (lane == (ap & 63)) va[ap >> 6] = -INFINITY;
            if (lane == (bp & 63)) vb[bp >> 6] = -INFINITY;
        }
        float ea = (lane < TK) ? expf(wva - m0a) : 0.0f;
        float eb = (lane < TK) ? expf(wvb - m0b) : 0.0f;
        float sa = ea, sb = eb;
        #pragma unroll
        for (int m = 1; m < 64; m <<= 1) {
            sa += __shfl_xor(sa, m, 64);
            sb += __shfl_xor(sb, m, 64);
        }
        if (lane < TK) {
            {
                const int bc = bc0 + ra;
                const size_t base = ((size_t)bc * Hh + h) * TK;
                const int a = wpa >> 5;
                // reference quirk: product_indices[a*32+b] = l[a]*N + r[a]
                const int fl = topi[0][ra][a] * Nk + topi[1][ra][a];
                out[base + lane] = ea / sa;
                out[(size_t)W_ELEMS + base + lane] = (float)fl;
            }
            {
                const int bc = bc0 + rb;
                const size_t base = ((size_t)bc * Hh + h) * TK;
                const int a = wpb >> 5;
                const int fl = topi[0][rb][a] * Nk + topi[1][rb][a];
                out[base + lane] = eb / sb;
                out[(size_t)W_ELEMS + base + lane] = (float)fl;
            }
        }
    }
}

extern "C" void kernel_launch(void* const* d_in, const int* in_sizes, int n_in,
                              void* d_out, int out_size, void* d_ws, size_t ws_size,
                              hipStream_t stream)
{
    const float* query = (const float*)d_in[0];
    const float* keyl  = (const float*)d_in[1];
    const float* keyr  = (const float*)d_in[2];
    float* out = (float*)d_out;
    pk_kernel<<<dim3(8192), dim3(NT), 0, stream>>>(query, keyl, keyr, out);
}

// Round 2
// 3460.419 us; speedup vs baseline: 1.1549x; 1.0863x over previous
//
#include <hip/hip_runtime.h>
#include <math.h>

#define Hh  8
#define Dd  512
#define SUB 256          // D/2
#define Nk  1024         // num_subkeys
#define TK  32           // top_k
#define Rr  8            // rows (b,c) per block
#define NT  256
#define W_ELEMS (65536 * 32)

// Phase-1 arithmetic: single accumulator per (row,key), strictly sequential
// FUSED-FMA chain over the contraction dim in natural order (d = 0..255).
// Bit-identical to the previous kernel; only data movement changed:
//   - query tile (8 rows x 512 f32 = 16 KB) staged to LDS ONCE, coalesced
//     (4 VMEM insts/thread instead of 4096 wave-uniform global dwordx4)
//   - phase-1 q reads are uniform-address ds_read_b128 (broadcast, 0-conflict)
// Tie-break everywhere: stable lowest-index (XLA TopK semantics).

__global__ __launch_bounds__(NT, 2)
void pk_kernel(const float* __restrict__ query,
               const float* __restrict__ keyl,
               const float* __restrict__ keyr,
               float* __restrict__ out)
{
    __shared__ float qs[Rr][Dd];          // 16 KB query tile
    __shared__ float sc[Rr][Nk];          // 32 KB scores
    __shared__ float topv[2][Rr][TK];     // 2 KB
    __shared__ int   topi[2][Rr][TK];     // 2 KB

    const int bid  = blockIdx.x;
    const int h    = bid >> 10;           // h-major for L2 key locality
    const int tile = bid & 1023;
    const int bc0  = tile * Rr;
    const int t    = threadIdx.x;
    const int lane = t & 63;
    const int wave = t >> 6;

    // ---- stage query tile to LDS, fully coalesced (4 dwordx4 per thread) ----
    #pragma unroll
    for (int rw = 0; rw < 2; ++rw) {
        const int r = wave * 2 + rw;
        const float4* src = (const float4*)(query + ((size_t)(bc0 + r) * Hh + h) * Dd);
        float4* dst = (float4*)qs[r];
        dst[lane]      = src[lane];
        dst[lane + 64] = src[lane + 64];
    }
    __syncthreads();

    for (int side = 0; side < 2; ++side) {
        const float* kbase = (side == 0 ? keyl : keyr) + (size_t)h * Nk * SUB;

        // ---- phase 1: sequential-FMA GEMV, keys from global, q from LDS ----
        for (int g = 0; g < 4; ++g) {
            const float4* krow = (const float4*)(kbase + (size_t)(g * 256 + t) * SUB);
            float acc[Rr] = {0.f, 0.f, 0.f, 0.f, 0.f, 0.f, 0.f, 0.f};

            #pragma unroll 2
            for (int js = 0; js < 16; ++js) {     // 16 steps x 16 floats
                // one full 64B line of this lane's key row, issued together
                float4 k0 = krow[4*js+0], k1 = krow[4*js+1],
                       k2 = krow[4*js+2], k3 = krow[4*js+3];
                #pragma unroll
                for (int r = 0; r < Rr; ++r) {
                    const float4* qv = (const float4*)&qs[r][side * SUB];
                    float4 q0 = qv[4*js+0], q1 = qv[4*js+1],
                           q2 = qv[4*js+2], q3 = qv[4*js+3];
                    float a = acc[r];
                    // strictly sequential fused chain, d ascending
                    a = fmaf(q0.x, k0.x, a); a = fmaf(q0.y, k0.y, a);
                    a = fmaf(q0.z, k0.z, a); a = fmaf(q0.w, k0.w, a);
                    a = fmaf(q1.x, k1.x, a); a = fmaf(q1.y, k1.y, a);
                    a = fmaf(q1.z, k1.z, a); a = fmaf(q1.w, k1.w, a);
                    a = fmaf(q2.x, k2.x, a); a = fmaf(q2.y, k2.y, a);
                    a = fmaf(q2.z, k2.z, a); a = fmaf(q2.w, k2.w, a);
                    a = fmaf(q3.x, k3.x, a); a = fmaf(q3.y, k3.y, a);
                    a = fmaf(q3.z, k3.z, a); a = fmaf(q3.w, k3.w, a);
                    acc[r] = a;
                }
            }
            #pragma unroll
            for (int r = 0; r < Rr; ++r)
                sc[r][g * 256 + t] = acc[r];
        }
        __syncthreads();

        // ---- phase 2: exact top-32 per row, two rows interleaved per wave ----
        {
            const int ra = wave, rb = wave + 4;
            float va[16], vb[16];
            #pragma unroll
            for (int i = 0; i < 16; ++i) {
                va[i] = sc[ra][lane + 64 * i];
                vb[i] = sc[rb][lane + 64 * i];
            }
            for (int it = 0; it < TK; ++it) {
                float av = va[0]; int ap = lane;
                float bv = vb[0]; int bp = lane;
                #pragma unroll
                for (int i = 1; i < 16; ++i) {
                    if (va[i] > av) { av = va[i]; ap = lane + 64 * i; }
                    if (vb[i] > bv) { bv = vb[i]; bp = lane + 64 * i; }
                }
                #pragma unroll
                for (int m = 1; m < 64; m <<= 1) {
                    float oav = __shfl_xor(av, m, 64); int oap = __shfl_xor(ap, m, 64);
                    float obv = __shfl_xor(bv, m, 64); int obp = __shfl_xor(bp, m, 64);
                    if (oav > av || (oav == av && oap < ap)) { av = oav; ap = oap; }
                    if (obv > bv || (obv == bv && obp < bp)) { bv = obv; bp = obp; }
                }
                if (lane == it) {
                    topv[side][ra][it] = av; topi[side][ra][it] = ap;
                    topv[side][rb][it] = bv; topi[side][rb][it] = bp;
                }
                if (lane == (ap & 63)) va[ap >> 6] = -INFINITY;
                if (lane == (bp & 63)) vb[bp >> 6] = -INFINITY;
            }
        }
        __syncthreads();
    }

    // ---- phase 3: 32x32 product sums, top-32, softmax; two rows interleaved ----
    {
        const int ra = wave, rb = wave + 4;
        float va[16], vb[16];
        #pragma unroll
        for (int i = 0; i < 16; ++i) {
            int pos = lane + 64 * i;                  // pos = a*32 + b
            va[i] = __fadd_rn(topv[0][ra][pos >> 5], topv[1][ra][pos & 31]);
            vb[i] = __fadd_rn(topv[0][rb][pos >> 5], topv[1][rb][pos & 31]);
        }
        float m0a = 0.0f, wva = 0.0f; int wpa = 0;
        float m0b = 0.0f, wvb = 0.0f; int wpb = 0;
        for (int it = 0; it < TK; ++it) {
            float av = va[0]; int ap = lane;
            float bv = vb[0]; int bp = lane;
            #pragma unroll
            for (int i = 1; i < 16; ++i) {
                if (va[i] > av) { av = va[i]; ap = lane + 64 * i; }
                if (vb[i] > bv) { bv = vb[i]; bp = lane + 64 * i; }
            }
            #pragma unroll
            for (int m = 1; m < 64; m <<= 1) {
                float oav = __shfl_xor(av, m, 64); int oap = __shfl_xor(ap, m, 64);
                float obv = __shfl_xor(bv, m, 64); int obp = __shfl_xor(bp, m, 64);
                if (oav > av || (oav == av && oap < ap)) { av = oav; ap = oap; }
                if (obv > bv || (obv == bv && obp < bp)) { bv = obv; bp = obp; }
            }
            if (it == 0) { m0a = av; m0b = bv; }      // rank 0 = max
            if (lane == it) { wva = av; wpa = ap; wvb = bv; wpb = bp; }
            if (lane == (ap & 63)) va[ap >> 6] = -INFINITY;
            if (lane == (bp & 63)) vb[bp >> 6] = -INFINITY;
        }
        float ea = (lane < TK) ? expf(wva - m0a) : 0.0f;
        float eb = (lane < TK) ? expf(wvb - m0b) : 0.0f;
        float sa = ea, sb = eb;
        #pragma unroll
        for (int m = 1; m < 64; m <<= 1) {
            sa += __shfl_xor(sa, m, 64);
            sb += __shfl_xor(sb, m, 64);
        }
        if (lane < TK) {
            {
                const int bc = bc0 + ra;
                const size_t base = ((size_t)bc * Hh + h) * TK;
                const int a = wpa >> 5;
                // reference quirk: product_indices[a*32+b] = l[a]*N + r[a]
                const int fl = topi[0][ra][a] * Nk + topi[1][ra][a];
                out[base + lane] = ea / sa;
                out[(size_t)W_ELEMS + base + lane] = (float)fl;
            }
            {
                const int bc = bc0 + rb;
                const size_t base = ((size_t)bc * Hh + h) * TK;
                const int a = wpb >> 5;
                const int fl = topi[0][rb][a] * Nk + topi[1][rb][a];
                out[base + lane] = eb / sb;
                out[(size_t)W_ELEMS + base + lane] = (float)fl;
            }
        }
    }
}

extern "C" void kernel_launch(void* const* d_in, const int* in_sizes, int n_in,
                              void* d_out, int out_size, void* d_ws, size_t ws_size,
                              hipStream_t stream)
{
    const float* query = (const float*)d_in[0];
    const float* keyl  = (const float*)d_in[1];
    const float* keyr  = (const float*)d_in[2];
    float* out = (float*)d_out;
    pk_kernel<<<dim3(8192), dim3(NT), 0, stream>>>(query, keyl, keyr, out);
}

// Round 3
// 3438.039 us; speedup vs baseline: 1.1624x; 1.0065x over previous
//
#include <hip/hip_runtime.h>
#include <math.h>

#define Hh  8
#define Dd  512
#define SUB 256          // D/2
#define Nk  1024         // num_subkeys
#define TK  32           // top_k
#define Rr  8            // rows (b,c) per block
#define NT  256
#define W_ELEMS (65536 * 32)

__device__ __forceinline__ void f4_to_arr(float4 v, float* a) {
    a[0] = v.x; a[1] = v.y; a[2] = v.z; a[3] = v.w;
}

// Phase-1 arithmetic: single accumulator per (row,key), strictly sequential
// FUSED-FMA chain over the contraction dim in natural order (d = 0..255).
// Bit-identical to previous kernels; only delivery changed:
//   - q is wave-uniform -> loaded ONCE via scalar loads (s_load, scalar pipe)
//     and consumed as the SGPR operand of v_fma. Phase-1 DS insts: ZERO.
//   - keys: per-lane rows, 64 B consumed per step (4 back-to-back dwordx4).
//   - js-outer loop: each q element loaded once total (not once per g).
// Tie-break everywhere: stable lowest-index (XLA TopK semantics).

__global__ __launch_bounds__(NT, 4)
void pk_kernel(const float* __restrict__ query,
               const float* __restrict__ keyl,
               const float* __restrict__ keyr,
               float* __restrict__ out)
{
    __shared__ float sc[Rr][Nk];          // 32 KB scores
    __shared__ float topv[2][Rr][TK];     // 2 KB
    __shared__ int   topi[2][Rr][TK];     // 2 KB

    const int bid  = blockIdx.x;
    const int h    = bid >> 10;           // h-major for L2 key locality
    const int tile = bid & 1023;
    const int bc0  = tile * Rr;
    const int t    = threadIdx.x;
    const int lane = t & 63;
    const int wave = t >> 6;

    for (int side = 0; side < 2; ++side) {
        const float* kbase = (side == 0 ? keyl : keyr) + (size_t)h * Nk * SUB;

        const float4* kr[4];              // this lane's 4 key rows
        #pragma unroll
        for (int g = 0; g < 4; ++g)
            kr[g] = (const float4*)(kbase + (size_t)(g * 256 + t) * SUB);

        const float4* qp[Rr];             // wave-uniform -> scalar loads
        #pragma unroll
        for (int r = 0; r < Rr; ++r)
            qp[r] = (const float4*)(query +
                ((size_t)(bc0 + r) * Hh + h) * Dd + side * SUB);

        float acc[Rr][4];
        #pragma unroll
        for (int r = 0; r < Rr; ++r)
            #pragma unroll
            for (int g = 0; g < 4; ++g) acc[r][g] = 0.0f;

        // ---- phase 1: sequential-FMA GEMV; q from SGPRs, k from VMEM ----
        for (int js = 0; js < 16; ++js) {         // 16 steps x 16 floats of d
            #pragma unroll
            for (int c = 0; c < 4; ++c) {         // 4-float sub-chunks
                float kk[4][4];
                #pragma unroll
                for (int g = 0; g < 4; ++g)
                    f4_to_arr(kr[g][4 * js + c], kk[g]);
                #pragma unroll
                for (int r = 0; r < Rr; ++r) {
                    float qq[4];
                    f4_to_arr(qp[r][4 * js + c], qq);   // uniform -> s_load
                    // per-(r,g) chain: d ascending, strictly sequential fused
                    #pragma unroll
                    for (int e = 0; e < 4; ++e) {
                        #pragma unroll
                        for (int g = 0; g < 4; ++g)
                            acc[r][g] = fmaf(qq[e], kk[g][e], acc[r][g]);
                    }
                }
            }
        }
        #pragma unroll
        for (int r = 0; r < Rr; ++r)
            #pragma unroll
            for (int g = 0; g < 4; ++g)
                sc[r][g * 256 + t] = acc[r][g];
        __syncthreads();

        // ---- phase 2: exact top-32 per row, two rows interleaved per wave ----
        {
            const int ra = wave, rb = wave + 4;
            float va[16], vb[16];
            #pragma unroll
            for (int i = 0; i < 16; ++i) {
                va[i] = sc[ra][lane + 64 * i];
                vb[i] = sc[rb][lane + 64 * i];
            }
            for (int it = 0; it < TK; ++it) {
                float av = va[0]; int ap = lane;
                float bv = vb[0]; int bp = lane;
                #pragma unroll
                for (int i = 1; i < 16; ++i) {
                    if (va[i] > av) { av = va[i]; ap = lane + 64 * i; }
                    if (vb[i] > bv) { bv = vb[i]; bp = lane + 64 * i; }
                }
                #pragma unroll
                for (int m = 1; m < 64; m <<= 1) {
                    float oav = __shfl_xor(av, m, 64); int oap = __shfl_xor(ap, m, 64);
                    float obv = __shfl_xor(bv, m, 64); int obp = __shfl_xor(bp, m, 64);
                    if (oav > av || (oav == av && oap < ap)) { av = oav; ap = oap; }
                    if (obv > bv || (obv == bv && obp < bp)) { bv = obv; bp = obp; }
                }
                if (lane == it) {
                    topv[side][ra][it] = av; topi[side][ra][it] = ap;
                    topv[side][rb][it] = bv; topi[side][rb][it] = bp;
                }
                if (lane == (ap & 63)) va[ap >> 6] = -INFINITY;
                if (lane == (bp & 63)) vb[bp >> 6] = -INFINITY;
            }
        }
        __syncthreads();
    }

    // ---- phase 3: 32x32 product sums, top-32, softmax; two rows interleaved ----
    {
        const int ra = wave, rb = wave + 4;
        float va[16], vb[16];
        #pragma unroll
        for (int i = 0; i < 16; ++i) {
            int pos = lane + 64 * i;                  // pos = a*32 + b
            va[i] = __fadd_rn(topv[0][ra][pos >> 5], topv[1][ra][pos & 31]);
            vb[i] = __fadd_rn(topv[0][rb][pos >> 5], topv[1][rb][pos & 31]);
        }
        float m0a = 0.0f, wva = 0.0f; int wpa = 0;
        float m0b = 0.0f, wvb = 0.0f; int wpb = 0;
        for (int it = 0; it < TK; ++it) {
            float av = va[0]; int ap = lane;
            float bv = vb[0]; int bp = lane;
            #pragma unroll
            for (int i = 1; i < 16; ++i) {
                if (va[i] > av) { av = va[i]; ap = lane + 64 * i; }
                if (vb[i] > bv) { bv = vb[i]; bp = lane + 64 * i; }
            }
            #pragma unroll
            for (int m = 1; m < 64; m <<= 1) {
                float oav = __shfl_xor(av, m, 64); int oap = __shfl_xor(ap, m, 64);
                float obv = __shfl_xor(bv, m, 64); int obp = __shfl_xor(bp, m, 64);
                if (oav > av || (oav == av && oap < ap)) { av = oav; ap = oap; }
                if (obv > bv || (obv == bv && obp < bp)) { bv = obv; bp = obp; }
            }
            if (it == 0) { m0a = av; m0b = bv; }      // rank 0 = max
            if (lane == it) { wva = av; wpa = ap; wvb = bv; wpb = bp; }
            if (lane == (ap & 63)) va[ap >> 6] = -INFINITY;
            if (lane == (bp & 63)) vb[bp >> 6] = -INFINITY;
        }
        float ea = (lane < TK) ? expf(wva - m0a) : 0.0f;
        float eb = (lane < TK) ? expf(wvb - m0b) : 0.0f;
        float sa = ea, sb = eb;
        #pragma unroll
        for (int m = 1; m < 64; m <<= 1) {
            sa += __shfl_xor(sa, m, 64);
            sb += __shfl_xor(sb, m, 64);
        }
        if (lane < TK) {
            {
                const int bc = bc0 + ra;
                const size_t base = ((size_t)bc * Hh + h) * TK;
                const int a = wpa >> 5;
                // reference quirk: product_indices[a*32+b] = l[a]*N + r[a]
                const int fl = topi[0][ra][a] * Nk + topi[1][ra][a];
                out[base + lane] = ea / sa;
                out[(size_t)W_ELEMS + base + lane] = (float)fl;
            }
            {
                const int bc = bc0 + rb;
                const size_t base = ((size_t)bc * Hh + h) * TK;
                const int a = wpb >> 5;
                const int fl = topi[0][rb][a] * Nk + topi[1][rb][a];
                out[base + lane] = eb / sb;
                out[(size_t)W_ELEMS + base + lane] = (float)fl;
            }
        }
    }
}

extern "C" void kernel_launch(void* const* d_in, const int* in_sizes, int n_in,
                              void* d_out, int out_size, void* d_ws, size_t ws_size,
                              hipStream_t stream)
{
    const float* query = (const float*)d_in[0];
    const float* keyl  = (const float*)d_in[1];
    const float* keyr  = (const float*)d_in[2];
    float* out = (float*)d_out;
    pk_kernel<<<dim3(8192), dim3(NT), 0, stream>>>(query, keyl, keyr, out);
}

// Round 4
// 3385.872 us; speedup vs baseline: 1.1803x; 1.0154x over previous
//
#include <hip/hip_runtime.h>
#include <math.h>

#define Hh  8
#define Dd  512
#define SUB 256          // D/2
#define Nk  1024         // num_subkeys
#define TK  32           // top_k
#define Rr  8            // rows (b,c) per block
#define NT  256
#define W_ELEMS (65536 * 32)

// Phase-1 arithmetic: single accumulator per (row,key), strictly sequential
// FUSED-FMA chain over the contraction dim in natural order (d = 0..255).
// Bit-identical to previous kernels; delivery structure:
//   - q staged once to LDS (16 KB, coalesced), then read as BROADCAST
//     ds_read_b128 ONCE per (js,c,row) feeding ALL 4 key groups
//     -> 1024 DS insts/thread (4x fewer than R2's per-g reload)
//   - keys direct from global, per-lane rows, 16B x 4 groups per step
//   - NO scalar-load q path (R3 spilled SGPRs -> 500 MB scratch traffic)
// Tie-break everywhere: stable lowest-index (XLA TopK semantics).

__global__ __launch_bounds__(NT, 3)
void pk_kernel(const float* __restrict__ query,
               const float* __restrict__ keyl,
               const float* __restrict__ keyr,
               float* __restrict__ out)
{
    __shared__ float qs[Rr][Dd];          // 16 KB query tile
    __shared__ float sc[Rr][Nk];          // 32 KB scores
    __shared__ float topv[2][Rr][TK];     // 2 KB
    __shared__ int   topi[2][Rr][TK];     // 2 KB

    const int bid  = blockIdx.x;
    const int h    = bid >> 10;           // h-major for L2 key locality
    const int tile = bid & 1023;
    const int bc0  = tile * Rr;
    const int t    = threadIdx.x;
    const int lane = t & 63;
    const int wave = t >> 6;

    // ---- stage query tile to LDS, fully coalesced (4 dwordx4 per thread) ----
    #pragma unroll
    for (int rw = 0; rw < 2; ++rw) {
        const int r = wave * 2 + rw;
        const float4* src = (const float4*)(query + ((size_t)(bc0 + r) * Hh + h) * Dd);
        float4* dst = (float4*)qs[r];
        dst[lane]      = src[lane];
        dst[lane + 64] = src[lane + 64];
    }
    __syncthreads();

    for (int side = 0; side < 2; ++side) {
        const float* kbase = (side == 0 ? keyl : keyr) + (size_t)h * Nk * SUB;

        const float4* kr0 = (const float4*)(kbase + (size_t)(0 * 256 + t) * SUB);
        const float4* kr1 = (const float4*)(kbase + (size_t)(1 * 256 + t) * SUB);
        const float4* kr2 = (const float4*)(kbase + (size_t)(2 * 256 + t) * SUB);
        const float4* kr3 = (const float4*)(kbase + (size_t)(3 * 256 + t) * SUB);

        float acc[Rr][4];
        #pragma unroll
        for (int r = 0; r < Rr; ++r)
            #pragma unroll
            for (int g = 0; g < 4; ++g) acc[r][g] = 0.0f;

        // ---- phase 1: q broadcast from LDS once per (js,c,row), 4 keys/thread ----
        #pragma unroll 2
        for (int js = 0; js < 16; ++js) {
            #pragma unroll
            for (int c = 0; c < 4; ++c) {
                const int idx = 4 * js + c;
                float4 k0 = kr0[idx], k1 = kr1[idx], k2 = kr2[idx], k3 = kr3[idx];
                #pragma unroll
                for (int r = 0; r < Rr; ++r) {
                    // one broadcast ds_read_b128 feeds 16 FMAs
                    float4 qv = ((const float4*)&qs[r][side * SUB])[idx];
                    // per-(r,g) chain: d ascending, strictly sequential fused
                    acc[r][0] = fmaf(qv.x, k0.x, acc[r][0]);
                    acc[r][1] = fmaf(qv.x, k1.x, acc[r][1]);
                    acc[r][2] = fmaf(qv.x, k2.x, acc[r][2]);
                    acc[r][3] = fmaf(qv.x, k3.x, acc[r][3]);
                    acc[r][0] = fmaf(qv.y, k0.y, acc[r][0]);
                    acc[r][1] = fmaf(qv.y, k1.y, acc[r][1]);
                    acc[r][2] = fmaf(qv.y, k2.y, acc[r][2]);
                    acc[r][3] = fmaf(qv.y, k3.y, acc[r][3]);
                    acc[r][0] = fmaf(qv.z, k0.z, acc[r][0]);
                    acc[r][1] = fmaf(qv.z, k1.z, acc[r][1]);
                    acc[r][2] = fmaf(qv.z, k2.z, acc[r][2]);
                    acc[r][3] = fmaf(qv.z, k3.z, acc[r][3]);
                    acc[r][0] = fmaf(qv.w, k0.w, acc[r][0]);
                    acc[r][1] = fmaf(qv.w, k1.w, acc[r][1]);
                    acc[r][2] = fmaf(qv.w, k2.w, acc[r][2]);
                    acc[r][3] = fmaf(qv.w, k3.w, acc[r][3]);
                }
            }
        }
        #pragma unroll
        for (int r = 0; r < Rr; ++r)
            #pragma unroll
            for (int g = 0; g < 4; ++g)
                sc[r][g * 256 + t] = acc[r][g];
        __syncthreads();

        // ---- phase 2: exact top-32 per row, two rows interleaved per wave ----
        {
            const int ra = wave, rb = wave + 4;
            float va[16], vb[16];
            #pragma unroll
            for (int i = 0; i < 16; ++i) {
                va[i] = sc[ra][lane + 64 * i];
                vb[i] = sc[rb][lane + 64 * i];
            }
            for (int it = 0; it < TK; ++it) {
                float av = va[0]; int ap = lane;
                float bv = vb[0]; int bp = lane;
                #pragma unroll
                for (int i = 1; i < 16; ++i) {
                    if (va[i] > av) { av = va[i]; ap = lane + 64 * i; }
                    if (vb[i] > bv) { bv = vb[i]; bp = lane + 64 * i; }
                }
                #pragma unroll
                for (int m = 1; m < 64; m <<= 1) {
                    float oav = __shfl_xor(av, m, 64); int oap = __shfl_xor(ap, m, 64);
                    float obv = __shfl_xor(bv, m, 64); int obp = __shfl_xor(bp, m, 64);
                    if (oav > av || (oav == av && oap < ap)) { av = oav; ap = oap; }
                    if (obv > bv || (obv == bv && obp < bp)) { bv = obv; bp = obp; }
                }
                if (lane == it) {
                    topv[side][ra][it] = av; topi[side][ra][it] = ap;
                    topv[side][rb][it] = bv; topi[side][rb][it] = bp;
                }
                if (lane == (ap & 63)) va[ap >> 6] = -INFINITY;
                if (lane == (bp & 63)) vb[bp >> 6] = -INFINITY;
            }
        }
        __syncthreads();
    }

    // ---- phase 3: 32x32 product sums, top-32, softmax; two rows interleaved ----
    {
        const int ra = wave, rb = wave + 4;
        float va[16], vb[16];
        #pragma unroll
        for (int i = 0; i < 16; ++i) {
            int pos = lane + 64 * i;                  // pos = a*32 + b
            va[i] = __fadd_rn(topv[0][ra][pos >> 5], topv[1][ra][pos & 31]);
            vb[i] = __fadd_rn(topv[0][rb][pos >> 5], topv[1][rb][pos & 31]);
        }
        float m0a = 0.0f, wva = 0.0f; int wpa = 0;
        float m0b = 0.0f, wvb = 0.0f; int wpb = 0;
        for (int it = 0; it < TK; ++it) {
            float av = va[0]; int ap = lane;
            float bv = vb[0]; int bp = lane;
            #pragma unroll
            for (int i = 1; i < 16; ++i) {
                if (va[i] > av) { av = va[i]; ap = lane + 64 * i; }
                if (vb[i] > bv) { bv = vb[i]; bp = lane + 64 * i; }
            }
            #pragma unroll
            for (int m = 1; m < 64; m <<= 1) {
                float oav = __shfl_xor(av, m, 64); int oap = __shfl_xor(ap, m, 64);
                float obv = __shfl_xor(bv, m, 64); int obp = __shfl_xor(bp, m, 64);
                if (oav > av || (oav == av && oap < ap)) { av = oav; ap = oap; }
                if (obv > bv || (obv == bv && obp < bp)) { bv = obv; bp = obp; }
            }
            if (it == 0) { m0a = av; m0b = bv; }      // rank 0 = max
            if (lane == it) { wva = av; wpa = ap; wvb = bv; wpb = bp; }
            if (lane == (ap & 63)) va[ap >> 6] = -INFINITY;
            if (lane == (bp & 63)) vb[bp >> 6] = -INFINITY;
        }
        float ea = (lane < TK) ? expf(wva - m0a) : 0.0f;
        float eb = (lane < TK) ? expf(wvb - m0b) : 0.0f;
        float sa = ea, sb = eb;
        #pragma unroll
        for (int m = 1; m < 64; m <<= 1) {
            sa += __shfl_xor(sa, m, 64);
            sb += __shfl_xor(sb, m, 64);
        }
        if (lane < TK) {
            {
                const int bc = bc0 + ra;
                const size_t base = ((size_t)bc * Hh + h) * TK;
                const int a = wpa >> 5;
                // reference quirk: product_indices[a*32+b] = l[a]*N + r[a]
                const int fl = topi[0][ra][a] * Nk + topi[1][ra][a];
                out[base + lane] = ea / sa;
                out[(size_t)W_ELEMS + base + lane] = (float)fl;
            }
            {
                const int bc = bc0 + rb;
                const size_t base = ((size_t)bc * Hh + h) * TK;
                const int a = wpb >> 5;
                const int fl = topi[0][rb][a] * Nk + topi[1][rb][a];
                out[base + lane] = eb / sb;
                out[(size_t)W_ELEMS + base + lane] = (float)fl;
            }
        }
    }
}

extern "C" void kernel_launch(void* const* d_in, const int* in_sizes, int n_in,
                              void* d_out, int out_size, void* d_ws, size_t ws_size,
                              hipStream_t stream)
{
    const float* query = (const float*)d_in[0];
    const float* keyl  = (const float*)d_in[1];
    const float* keyr  = (const float*)d_in[2];
    float* out = (float*)d_out;
    pk_kernel<<<dim3(8192), dim3(NT), 0, stream>>>(query, keyl, keyr, out);
}